// Round 1
// baseline (401.645 us; speedup 1.0000x reference)
//
#include <hip/hip_runtime.h>
#include <hip/hip_bf16.h>

// Problem constants (fixed by setup_inputs)
#define M_ROWS 262144   // B*A*T = 16*64*256
#define TILE_M 64
#define BK 32
#define REP 64          // second-level stats partials (matches finalize_k layout)
#define NBLOCKS 256     // persistent fused kernel: 1 block per CU
#define INVM (1.0f / 262144.0f)

typedef unsigned short ushort_t;
typedef unsigned int uint_t;
typedef __attribute__((ext_vector_type(8))) short short8_t;   // 8 bf16 = 4 VGPRs
typedef __attribute__((ext_vector_type(4))) float float4_t;   // MFMA acc

// bf16 (stored as ushort) <-> fp32 helpers. Load is exact; store is RNE.
__device__ __forceinline__ float b2f(ushort_t u) {
    union { uint_t i; float f; } c; c.i = ((uint_t)u) << 16; return c.f;
}
__device__ __forceinline__ ushort_t f2b(float f) {
    union { float f; uint_t i; } c; c.f = f;
    uint_t u = c.i;
    return (ushort_t)((u + 0x7fffu + ((u >> 16) & 1u)) >> 16);
}
// packed 2xfp32 -> 2xbf16 (v_cvt_pk_bf16_f32 on gfx950, RNE)
__device__ __forceinline__ uint_t pack2(float a, float b) {
    union { __hip_bfloat162 h; uint_t u; } c;
    c.h = __float22bfloat162_rn(make_float2(a, b));
    return c.u;
}

// async global->LDS DMA, 16 B per lane; data lands at ldsbase + lane*16
__device__ __forceinline__ void gld_lds16(const ushort_t* g, ushort_t* l) {
    __builtin_amdgcn_global_load_lds((const __attribute__((address_space(1))) void*)g,
                                     (__attribute__((address_space(3))) void*)l, 16, 0, 0);
}

// ---------------------------------------------------------------------------
// Persistent fused L1..L4 kernel (cooperative).
// Grid = 256 blocks x 512 threads; block b owns rows [b*1024, (b+1)*1024) =
// 4 whole (ba) sequences, so cummax is block-local. The ONLY cross-block
// dependency is BN batch stats -> 3 grid barriers + device-scope atomics.
// y1/y2/y3 round-trip global but each block re-reads its OWN rows (same CU /
// same L2 -> no cross-XCD coherence issue).
// ---------------------------------------------------------------------------
struct __attribute__((aligned(16))) SmemT {
    ushort_t Ws[128 * 256];   // 64 KB  weight tile (N x K bf16, XOR-swizzled)
    ushort_t Atile[64 * 256]; // 32 KB  A tile (64 rows x K, XOR-swizzled)
    char     Scratch[16384];  // 16 KB  epi bounce / phase-3 act staging
    float    sred[2048];      //  8 KB  stats cross-wave reduce
    float    gt[512];         //  2 KB  scan group totals [4][128]
    float    carry[128];      //        scan running carry per col
    float    s_sc[128];
    float    s_sh[128];
};

__device__ __forceinline__ void grid_sync(unsigned* cnt) {
    __syncthreads();
    if (threadIdx.x == 0) {
        __threadfence();
        __hip_atomic_fetch_add(cnt, 1u, __ATOMIC_ACQ_REL, __HIP_MEMORY_SCOPE_AGENT);
        while (__hip_atomic_load(cnt, __ATOMIC_ACQUIRE, __HIP_MEMORY_SCOPE_AGENT) < (unsigned)NBLOCKS) {
            __builtin_amdgcn_s_sleep(2);
        }
    }
    __syncthreads();
}

__device__ __forceinline__ void compute_scsh(SmemT& sm, const float* accum,
                                             const float* g, const float* be) {
    int f = threadIdx.x;
    if (f < 128) {
        float s = __hip_atomic_load(accum + f, __ATOMIC_RELAXED, __HIP_MEMORY_SCOPE_AGENT);
        float q = __hip_atomic_load(accum + 128 + f, __ATOMIC_RELAXED, __HIP_MEMORY_SCOPE_AGENT);
        float mean = s * INVM;
        float var = q * INVM - mean * mean;
        float sc = g[f] * rsqrtf(var + 1e-5f);
        sm.s_sc[f] = sc;
        sm.s_sh[f] = fmaf(-mean, sc, be[f]);
    }
    __syncthreads();
}

// One layer pass over this block's 16 row-tiles of 64 rows.
//  KW: GEMM K (256 for L1 concat, else 128). NW: output cols (128 or 64).
//  SCAN: apply causal cummax to act'd input. CONCAT: A = [act | cummax] (L1).
//  Act (scale/shift/relu from s_sc/s_sh) is applied ONCE per input element
//  during register staging -- no per-MFMA-fragment activation.
template<int KW, int NW, bool SCAN, bool CONCAT, bool STATS, bool OUTF32>
__device__ __forceinline__ void phase_run(SmemT& sm, const ushort_t* __restrict__ Yin,
                                          char* __restrict__ Yout,
                                          const ushort_t* __restrict__ WT,
                                          const float* __restrict__ bias,
                                          float* __restrict__ accum, int row0) {
    constexpr int NT = (NW == 128) ? 2 : 1;
    constexpr int ROWB = 2 * KW;          // A-tile row bytes (512 or 256)
    const int tid = threadIdx.x;
    const int lane = tid & 63;
    const int wave = tid >> 6;            // 0..7
    const int wm = wave & 1, wn = wave >> 1;
    const int quad = lane >> 4, l16 = lane & 15;

    // ---- stage weights (NW x KW bf16) via DMA, source pre-swizzled ----
    if constexpr (KW == 256) {
        #pragma unroll
        for (int i = 0; i < 8; ++i) {
            int t = i * 8 + wave;
            int r = t * 2 + (lane >> 5);
            int jd = lane & 31;
            int js = (jd & 16) | ((jd ^ (r & 15)) & 15);
            gld_lds16(WT + (size_t)r * KW + js * 8, sm.Ws + t * 512);
        }
    } else {
        constexpr int GROUPS = NW * KW * 2 / 1024;
        #pragma unroll
        for (int i = 0; i < GROUPS / 8; ++i) {
            int t = i * 8 + wave;
            int r = t * 4 + (lane >> 4);
            int js = (lane & 15) ^ (r & 15);
            gld_lds16(WT + (size_t)r * KW + js * 8, sm.Ws + t * 512);
        }
    }

    // staging geometry: thread -> (row, 16-col slice) of the 64x128 input tile
    const int sr = tid >> 3;
    const int col0 = (tid & 7) * 16;
    float scr[16], shr[16];
    #pragma unroll
    for (int e = 0; e < 16; ++e) { scr[e] = sm.s_sc[col0 + e]; shr[e] = sm.s_sh[col0 + e]; }

    float bvs[NT];
    #pragma unroll
    for (int nt = 0; nt < NT; ++nt) {
        int col = (NW == 128) ? (wn * 32 + nt * 16 + l16) : (wn * 16 + l16);
        bvs[nt] = bias[col];
    }
    float sSum[NT], sSq[NT];
    #pragma unroll
    for (int nt = 0; nt < NT; ++nt) { sSum[nt] = 0.f; sSq[nt] = 0.f; }

    // preload tile 0 into regs
    const uint4* p0 = (const uint4*)(Yin + (size_t)(row0 + sr) * 128 + col0);
    uint4 cA = p0[0], cB = p0[1];

    for (int t = 0; t < 16; ++t) {
        uint4 nA = cA, nB = cB;
        if (t + 1 < 16) {  // prefetch next tile (reg-staged)
            const uint4* pn = (const uint4*)(Yin + (size_t)(row0 + (t + 1) * 64 + sr) * 128 + col0);
            nA = pn[0]; nB = pn[1];
        }
        // ---- activation on current regs -> LDS (swizzled) ----
        {
            ushort_t u[16];
            *(uint4*)u = cA; *(uint4*)(u + 8) = cB;
            uint_t w[8];
            #pragma unroll
            for (int e = 0; e < 8; ++e) {
                float v0 = fmaxf(fmaf(b2f(u[2 * e]),     scr[2 * e],     shr[2 * e]),     0.f);
                float v1 = fmaxf(fmaf(b2f(u[2 * e + 1]), scr[2 * e + 1], shr[2 * e + 1]), 0.f);
                w[e] = pack2(v0, v1);
            }
            char* dst = (SCAN && !CONCAT) ? sm.Scratch : (char*)sm.Atile;
            const int drb = (SCAN && !CONCAT) ? 256 : ROWB;
            int c0 = (tid & 7) * 2;
            *(uint4*)(dst + sr * drb + ((c0 ^ (sr & 15)) * 16))       = *(uint4*)&w[0];
            *(uint4*)(dst + sr * drb + (((c0 + 1) ^ (sr & 15)) * 16)) = *(uint4*)&w[4];
        }
        __syncthreads();  // b1: act'd tile (and weight DMA) resident

        if constexpr (SCAN) {
            // per-column causal cummax over the 64-row tile; thread = (col, 16-row group)
            const int c = tid & 127, g = tid >> 7;
            const char* srcB = CONCAT ? (const char*)sm.Atile : (const char*)sm.Scratch;
            const int srb = CONCAT ? 512 : 256;
            float pv[16];
            float run = 0.f;   // act values are >=0, so 0 is the identity
            #pragma unroll
            for (int i = 0; i < 16; ++i) {
                int r = g * 16 + i;
                ushort_t uu = *(const ushort_t*)(srcB + r * srb +
                              (((c >> 3) ^ (r & 15)) & 15) * 16 + (c & 7) * 2);
                run = fmaxf(run, b2f(uu));
                pv[i] = run;
            }
            sm.gt[g * 128 + c] = run;
            __syncthreads();  // b2: group totals visible
            float off = (t & 3) ? sm.carry[c] : 0.f;   // sequence boundary every 4 tiles
            for (int gg = 0; gg < g; ++gg) off = fmaxf(off, sm.gt[gg * 128 + c]);
            float nc = fmaxf(off, run);
            {
                char* dstB = (char*)sm.Atile;
                const int hb = CONCAT ? 256 : 0;       // right half of A1 for L1
                #pragma unroll
                for (int i = 0; i < 16; ++i) {
                    int r = g * 16 + i;
                    *(ushort_t*)(dstB + r * ROWB + hb +
                        (((c >> 3) ^ (r & 15)) & 15) * 16 + (c & 7) * 2) = f2b(fmaxf(pv[i], off));
                }
            }
            __syncthreads();  // b3: P visible; carry reads done
            if (g == 3) sm.carry[c] = nc;
        }

        // ---- MFMA GEMM: 64 x NW x KW ----
        float4_t acc[2][NT];
        #pragma unroll
        for (int mt = 0; mt < 2; ++mt)
            #pragma unroll
            for (int nt = 0; nt < NT; ++nt) acc[mt][nt] = (float4_t)0.f;
        #pragma unroll
        for (int kk = 0; kk < KW / 32; ++kk) {
            int j = kk * 4 + quad;
            short8_t af[2];
            #pragma unroll
            for (int mt = 0; mt < 2; ++mt) {
                int r = wm * 32 + mt * 16 + l16;
                int js = (j & 16) | ((j ^ (r & 15)) & 15);
                af[mt] = *(const short8_t*)&sm.Atile[r * KW + js * 8];
            }
            #pragma unroll
            for (int nt = 0; nt < NT; ++nt) {
                int br = (NW == 128) ? (wn * 32 + nt * 16 + l16) : (wn * 16 + l16);
                int js = (j & 16) | ((j ^ (br & 15)) & 15);
                short8_t bf = *(const short8_t*)&sm.Ws[br * KW + js * 8];
                acc[0][nt] = __builtin_amdgcn_mfma_f32_16x16x32_bf16(af[0], bf, acc[0][nt], 0, 0, 0);
                acc[1][nt] = __builtin_amdgcn_mfma_f32_16x16x32_bf16(af[1], bf, acc[1][nt], 0, 0, 0);
            }
        }

        // ---- epilogue: bias, stats, swizzled LDS bounce ----
        #pragma unroll
        for (int mt = 0; mt < 2; ++mt)
            #pragma unroll
            for (int nt = 0; nt < NT; ++nt)
                #pragma unroll
                for (int rr = 0; rr < 4; ++rr) {
                    float v = acc[mt][nt][rr] + bvs[nt];
                    if constexpr (STATS) { sSum[nt] += v; sSq[nt] = fmaf(v, v, sSq[nt]); }
                    int row = wm * 32 + mt * 16 + quad * 4 + rr;
                    int col = (NW == 128) ? (wn * 32 + nt * 16 + l16) : (wn * 16 + l16);
                    if constexpr (OUTF32)
                        *(float*)(sm.Scratch + row * 256 +
                            (((col >> 2) ^ (row & 15)) & 15) * 16 + (col & 3) * 4) = v;
                    else
                        *(ushort_t*)(sm.Scratch + row * 256 +
                            (((col >> 3) ^ (row & 15)) & 15) * 16 + (col & 7) * 2) = f2b(v);
                }
        __syncthreads();  // b4: epi tile resident
        {
            size_t gr0 = (size_t)row0 + (size_t)t * 64;
            #pragma unroll
            for (int p = 0; p < 2; ++p) {
                int idx = p * 512 + tid;
                int row = idx >> 4, gch = idx & 15;
                uint4 v = *(const uint4*)(sm.Scratch + row * 256 + ((gch ^ (row & 15)) << 4));
                if constexpr (OUTF32)
                    *(uint4*)((float*)Yout + (gr0 + row) * 64 + gch * 4) = v;
                else
                    *(uint4*)((ushort_t*)Yout + (gr0 + row) * 128 + gch * 8) = v;
            }
        }
        __syncthreads();  // b5: Scratch reads done before next tile's overwrite
        cA = nA; cB = nB;
    }

    if constexpr (STATS) {
        #pragma unroll
        for (int nt = 0; nt < NT; ++nt) {
            float s = sSum[nt], q = sSq[nt];
            s += __shfl_xor(s, 16); q += __shfl_xor(q, 16);
            s += __shfl_xor(s, 32); q += __shfl_xor(q, 32);
            if (lane < 16) {
                int col = wn * 32 + nt * 16 + l16;
                sm.sred[(wave * 128 + col) * 2 + 0] = s;
                sm.sred[(wave * 128 + col) * 2 + 1] = q;
            }
        }
        __syncthreads();
        if (tid < 256) {
            int col = tid & 127, qs = tid >> 7;
            int wb = (col >> 5) * 2;  // the two wm-waves covering this col range
            float v = sm.sred[((wb * 128) + col) * 2 + qs] +
                      sm.sred[(((wb + 1) * 128) + col) * 2 + qs];
            atomicAdd(accum + qs * 128 + col, v);
        }
    }
}

__launch_bounds__(512, 2)
__global__ void fused_k(ushort_t* h0, ushort_t* h1,
                        const ushort_t* wt1, const ushort_t* wt2,
                        const ushort_t* wt3, const ushort_t* wt4,
                        const float* b1, const float* b2, const float* b3, const float* b4,
                        const float* g1, const float* be1, const float* g2, const float* be2,
                        const float* g3, const float* be3,
                        const float* sc0, const float* sh0,
                        float* accum, float* out, unsigned* cnts) {
    __shared__ SmemT sm;
    const int row0 = blockIdx.x * 1024;  // 4 sequences per block

    if (threadIdx.x < 128) {
        sm.s_sc[threadIdx.x] = sc0[threadIdx.x];
        sm.s_sh[threadIdx.x] = sh0[threadIdx.x];
    }
    __syncthreads();
    // L1: y1 = [bnrelu0(y0), cummax(bnrelu0(y0))] @ W1 + b1   (h0 -> h1)
    phase_run<256, 128, true, true, true, false>(sm, h0, (char*)h1, wt1, b1, accum, row0);
    grid_sync(cnts + 0);
    compute_scsh(sm, accum, g1, be1);
    // L2: y2 = bnrelu1(y1) @ W2 + b2                          (h1 -> h0)
    phase_run<128, 128, false, false, true, false>(sm, h1, (char*)h0, wt2, b2, accum + 256, row0);
    grid_sync(cnts + 1);
    compute_scsh(sm, accum + 256, g2, be2);
    // L3: y3 = cummax(bnrelu2(y2)) @ W3 + b3                  (h0 -> h1)
    phase_run<128, 128, true, false, true, false>(sm, h0, (char*)h1, wt3, b3, accum + 512, row0);
    grid_sync(cnts + 2);
    compute_scsh(sm, accum + 512, g3, be3);
    // L4: out = bnrelu3(y3) @ W4 + b4 (fp32)                  (h1 -> out)
    phase_run<128, 64, false, false, false, true>(sm, h1, (char*)out, wt4, b4, nullptr, row0);
}

// ---------------------------------------------------------------------------
// fp32 vector GEMM (layer 0: K=32, fp32 input) with fused stats partials.
// ---------------------------------------------------------------------------
template<int K, int N>
__launch_bounds__(256)
__global__ void gemm_f32_k(const float* __restrict__ A, const float* __restrict__ W,
                           const float* __restrict__ bias, ushort_t* __restrict__ C,
                           float* __restrict__ sumP, float* __restrict__ sqP) {
    constexpr int TX = N / 4;        // 32
    constexpr int TY = 256 / TX;     // 8
    constexpr int RM = TILE_M / TY;  // 8

    __shared__ float As[TILE_M][BK + 1];
    __shared__ float Ws[BK][N];
    __shared__ float redst[2][TY][N];

    const int tid = threadIdx.x;
    const int tx = tid % TX;
    const int ty = tid / TX;
    const int row0 = blockIdx.x * TILE_M;
    const int arow = tid >> 2;
    const int acol = (tid & 3) * 8;

    float acc[RM][4];
    #pragma unroll
    for (int r = 0; r < RM; ++r)
        #pragma unroll
        for (int c = 0; c < 4; ++c) acc[r][c] = 0.f;

    for (int k0 = 0; k0 < K; k0 += BK) {
        {
            const float4* p = (const float4*)&A[(size_t)(row0 + arow) * K + k0 + acol];
            float4 x0 = p[0], x1 = p[1];
            As[arow][acol + 0] = x0.x; As[arow][acol + 1] = x0.y;
            As[arow][acol + 2] = x0.z; As[arow][acol + 3] = x0.w;
            As[arow][acol + 4] = x1.x; As[arow][acol + 5] = x1.y;
            As[arow][acol + 6] = x1.z; As[arow][acol + 7] = x1.w;
        }
        #pragma unroll
        for (int i = 0; i < (BK * N) / 256; ++i) {
            int e = i * 256 + tid;
            Ws[e / N][e % N] = W[(size_t)(k0 + e / N) * N + e % N];
        }
        __syncthreads();
        #pragma unroll
        for (int kk = 0; kk < BK; ++kk) {
            float4 wv = *(const float4*)&Ws[kk][tx * 4];
            #pragma unroll
            for (int r = 0; r < RM; ++r) {
                float a = As[ty * RM + r][kk];
                acc[r][0] = fmaf(a, wv.x, acc[r][0]);
                acc[r][1] = fmaf(a, wv.y, acc[r][1]);
                acc[r][2] = fmaf(a, wv.z, acc[r][2]);
                acc[r][3] = fmaf(a, wv.w, acc[r][3]);
            }
        }
        __syncthreads();
    }
    float4 bv = *(const float4*)&bias[tx * 4];
    float s[4] = {0, 0, 0, 0}, q[4] = {0, 0, 0, 0};
    #pragma unroll
    for (int r = 0; r < RM; ++r) {
        float o[4];
        o[0] = acc[r][0] + bv.x; o[1] = acc[r][1] + bv.y;
        o[2] = acc[r][2] + bv.z; o[3] = acc[r][3] + bv.w;
        #pragma unroll
        for (int c = 0; c < 4; ++c) { s[c] += o[c]; q[c] = fmaf(o[c], o[c], q[c]); }
        size_t off = (size_t)(row0 + ty * RM + r) * N + tx * 4;
        uint2 ov;
        ov.x = pack2(o[0], o[1]);
        ov.y = pack2(o[2], o[3]);
        *(uint2*)&C[off] = ov;
    }
    #pragma unroll
    for (int c = 0; c < 4; ++c) {
        redst[0][ty][tx * 4 + c] = s[c];
        redst[1][ty][tx * 4 + c] = q[c];
    }
    __syncthreads();
    {
        int col = tid & (N - 1), qs = tid / N;
        float v = 0.f;
        #pragma unroll
        for (int t = 0; t < TY; ++t) v += redst[qs][t][col];
        (qs ? sqP : sumP)[(size_t)blockIdx.x * N + col] = v;
    }
}

// ---------------------------------------------------------------------------
// Tree-reduce block partials: P[NBLK][128] -> R2[col*64 + chunk] (64 chunks).
// ---------------------------------------------------------------------------
template<int NBLK>
__global__ __launch_bounds__(256) void reduce1_k(const float* __restrict__ sumP,
                                                 const float* __restrict__ sqP,
                                                 float* __restrict__ sumR2,
                                                 float* __restrict__ sqR2) {
    constexpr int ROWS = NBLK / 64;
    const int tid = threadIdx.x;
    const int qs = blockIdx.x & 1;
    const int chunk = blockIdx.x >> 1;
    const float* src = qs ? sqP : sumP;
    float* dst = qs ? sqR2 : sumR2;
    const int col = tid & 127;
    const int half = tid >> 7;
    float s = 0.f;
    for (int r = half; r < ROWS; r += 2)
        s += src[(size_t)(chunk * ROWS + r) * 128 + col];
    __shared__ float red[256];
    red[tid] = s;
    __syncthreads();
    if (tid < 128) dst[col * 64 + chunk] = red[tid] + red[tid + 128];
}

// Reduce 64 chunks; scale = g*rsqrt(var+eps); shift = be - mean*scale
__global__ void finalize_k(const float* __restrict__ sumR2, const float* __restrict__ sqR2,
                           const float* __restrict__ g, const float* __restrict__ be,
                           float* __restrict__ scale, float* __restrict__ shift) {
    const int f = threadIdx.x;  // 128
    const float4* ps = (const float4*)&sumR2[f * REP];
    const float4* pq = (const float4*)&sqR2[f * REP];
    float s = 0.f, q = 0.f;
    #pragma unroll
    for (int i = 0; i < REP / 4; ++i) {
        float4 a = ps[i]; s += (a.x + a.y) + (a.z + a.w);
        float4 b = pq[i]; q += (b.x + b.y) + (b.z + b.w);
    }
    const float invM = 1.f / (float)M_ROWS;
    float mean = s * invM;
    float var = q * invM - mean * mean;
    float sc = g[f] * rsqrtf(var + 1e-5f);
    scale[f] = sc;
    shift[f] = fmaf(-mean, sc, be[f]);
}

// All four weight transposes in one launch: fp32 W[K][N] -> bf16 WT[N][K]
__global__ void transpose_all_k(const float* __restrict__ W1, const float* __restrict__ W2,
                                const float* __restrict__ W3, const float* __restrict__ W4,
                                ushort_t* __restrict__ wt1, ushort_t* __restrict__ wt2,
                                ushort_t* __restrict__ wt3, ushort_t* __restrict__ wt4) {
    int idx = blockIdx.x * 256 + threadIdx.x;
    if (idx < 32768) {                       // W1: 256 x 128
        int k = idx >> 7, n = idx & 127;
        wt1[(size_t)n * 256 + k] = f2b(W1[idx]);
    } else if (idx < 49152) {                // W2: 128 x 128
        int i = idx - 32768;
        int k = i >> 7, n = i & 127;
        wt2[(size_t)n * 128 + k] = f2b(W2[i]);
    } else if (idx < 65536) {                // W3: 128 x 128
        int i = idx - 49152;
        int k = i >> 7, n = i & 127;
        wt3[(size_t)n * 128 + k] = f2b(W3[i]);
    } else if (idx < 73728) {                // W4: 128 x 64
        int i = idx - 65536;
        int k = i >> 6, n = i & 63;
        wt4[(size_t)n * 128 + k] = f2b(W4[i]);
    }
}

extern "C" void kernel_launch(void* const* d_in, const int* in_sizes, int n_in,
                              void* d_out, int out_size, void* d_ws, size_t ws_size,
                              hipStream_t stream) {
    const float* poly = (const float*)d_in[0];
    const float* W0 = (const float*)d_in[1];
    const float* b0 = (const float*)d_in[2];
    const float* g0 = (const float*)d_in[3];
    const float* be0 = (const float*)d_in[4];
    const float* W1 = (const float*)d_in[5];
    const float* b1 = (const float*)d_in[6];
    const float* g1 = (const float*)d_in[7];
    const float* be1 = (const float*)d_in[8];
    const float* W2 = (const float*)d_in[9];
    const float* b2 = (const float*)d_in[10];
    const float* g2 = (const float*)d_in[11];
    const float* be2 = (const float*)d_in[12];
    const float* W3 = (const float*)d_in[13];
    const float* b3 = (const float*)d_in[14];
    const float* g3 = (const float*)d_in[15];
    const float* be3 = (const float*)d_in[16];
    const float* W4 = (const float*)d_in[17];
    const float* b4 = (const float*)d_in[18];
    float* outp = (float*)d_out;

    float* st = (float*)d_ws;
    float* sumP = st;
    float* sqP = st + 524288;
    float* sumR2 = st + 1048576;
    float* sqR2 = sumR2 + 8192;
    float* scsh = st + 1064960;
    ushort_t* wt1 = (ushort_t*)((char*)d_ws + 4263936);         // 128 x 256
    ushort_t* wt2 = wt1 + 128 * 256;                            // 128 x 128
    ushort_t* wt3 = wt2 + 128 * 128;                            // 128 x 128
    ushort_t* wt4 = wt3 + 128 * 128;                            // 64 x 128
    ushort_t* h0 = (ushort_t*)((char*)d_ws + 4263936 + 147456);
    ushort_t* h1 = h0 + (size_t)M_ROWS * 128;

    const int G64 = M_ROWS / TILE_M;    // 4096 (L0)

    transpose_all_k<<<288, 256, 0, stream>>>(W1, W2, W3, W4, wt1, wt2, wt3, wt4);

    // Layer 0 (fp32 precision): y0 = poly @ W0 + b0 -> h0 (raw bf16) + partials
    gemm_f32_k<32, 128><<<G64, 256, 0, stream>>>(poly, W0, b0, h0, sumP, sqP);
    reduce1_k<4096><<<128, 256, 0, stream>>>(sumP, sqP, sumR2, sqR2);
    finalize_k<<<1, 128, 0, stream>>>(sumR2, sqR2, g0, be0, scsh, scsh + 128);

    // zero fused-kernel stat accumulators (3 layers x 256) + 3 barrier counters
    hipMemsetAsync(sumR2, 0, (768 + 8) * sizeof(float), stream);
    float* accum = sumR2;
    unsigned* cnts = (unsigned*)(sumR2 + 768);
    const float* sc0 = scsh;
    const float* sh0 = scsh + 128;

    // Persistent cooperative kernel: L1..L4 + both scans + all BN stats
    void* args[] = { &h0, &h1, &wt1, &wt2, &wt3, &wt4,
                     &b1, &b2, &b3, &b4,
                     &g1, &be1, &g2, &be2, &g3, &be3,
                     &sc0, &sh0, &accum, &outp, &cnts };
    hipLaunchCooperativeKernel((void*)fused_k, dim3(NBLOCKS), dim3(512), args, 0, stream);
}